// Round 1
// baseline (291.145 us; speedup 1.0000x reference)
//
#include <hip/hip_runtime.h>
#include <math.h>

#define N_NODES  100000
#define N_PATHS  1000000
#define E_TOT    8000000
#define NF       9          // rfft bins for n=16
#define NODE_STRIDE 10      // float2 per node (9 used + 1 pad for 16B alignment)

// cos/sin(2*pi*k/16)
__device__ __constant__ float COS16[16] = {
  1.0f,  0.92387953f,  0.70710678f,  0.38268343f,  0.0f, -0.38268343f, -0.70710678f, -0.92387953f,
 -1.0f, -0.92387953f, -0.70710678f, -0.38268343f,  0.0f,  0.38268343f,  0.70710678f,  0.92387953f };
__device__ __constant__ float SIN16[16] = {
  0.0f,  0.38268343f,  0.70710678f,  0.92387953f,  1.0f,  0.92387953f,  0.70710678f,  0.38268343f,
  0.0f, -0.38268343f, -0.70710678f, -0.92387953f, -1.0f, -0.92387953f, -0.70710678f, -0.38268343f };

// Stage 1: per-node IRF -> rfft(16) -> complex log, stored as [N][NODE_STRIDE] float2
__global__ void node_logfreq_kernel(const float* __restrict__ params,
                                    float2* __restrict__ lg) {
    int n = blockIdx.x * blockDim.x + threadIdx.x;
    if (n >= N_NODES) return;
    float k = params[n] + 0.5f;
    float inv_k = 1.0f / k;
    float x[16];
#pragma unroll
    for (int t = 0; t < 16; t++)
        x[t] = expf(-(float)t * inv_k) * inv_k;

    float2* dst = lg + (size_t)n * NODE_STRIDE;
#pragma unroll
    for (int f = 0; f < NF; f++) {
        float xr = 0.0f, xi = 0.0f;
#pragma unroll
        for (int t = 0; t < 16; t++) {
            int kk = (f * t) & 15;
            xr = fmaf(x[t], COS16[kk], xr);
            xi = fmaf(-x[t], SIN16[kk], xi);   // e^{-i*2pi*f*t/16}
        }
        float lr = 0.5f * logf(fmaf(xr, xr, xi * xi));
        float li = atan2f(xi, xr);
        dst[f] = make_float2(lr, li);
    }
}

__device__ __forceinline__ int lower_bound(const int* __restrict__ a, int n, int v) {
    int lo = 0, hi = n;
    while (lo < hi) {
        int m = (lo + hi) >> 1;
        if (a[m] < v) lo = m + 1; else hi = m;
    }
    return lo;
}

// Stage 2: one thread per path. Segment-sum logs, exp, irfft(16), relu, flip, normalize.
__global__ void path_kernel(const int* __restrict__ pidx,
                            const int* __restrict__ pnode,
                            const float2* __restrict__ lg,
                            float* __restrict__ out) {
    int p = blockIdx.x * blockDim.x + threadIdx.x;
    if (p >= N_PATHS) return;

    int start = lower_bound(pidx, E_TOT, p);
    int end   = lower_bound(pidx, E_TOT, p + 1);

    float re[NF], im[NF];
#pragma unroll
    for (int f = 0; f < NF; f++) { re[f] = 0.0f; im[f] = 0.0f; }

    for (int e = start; e < end; e++) {
        int node = pnode[e];
        const float4* p4 = (const float4*)(lg + (size_t)node * NODE_STRIDE);
        float4 a = p4[0], b = p4[1], c = p4[2], d = p4[3];
        float2 e2 = *(const float2*)(p4 + 4);
        re[0] += a.x;  im[0] += a.y;
        re[1] += a.z;  im[1] += a.w;
        re[2] += b.x;  im[2] += b.y;
        re[3] += b.z;  im[3] += b.w;
        re[4] += c.x;  im[4] += c.y;
        re[5] += c.z;  im[5] += c.w;
        re[6] += d.x;  im[6] += d.y;
        re[7] += d.z;  im[7] += d.w;
        re[8] += e2.x; im[8] += e2.y;
    }

    // complex exp
    float Xr[NF], Xi[NF];
#pragma unroll
    for (int f = 0; f < NF; f++) {
        float mag = expf(re[f]);
        float s, c;
        sincosf(im[f], &s, &c);
        Xr[f] = mag * c;
        Xi[f] = mag * s;
    }

    // irfft n=16: x[t] = (1/16)[X0 + (-1)^t X8 + 2 * sum_{f=1..7} (Xr cos - Xi sin)(2pi f t/16)]
    float xt[16];
    float ssum = 0.0f;
#pragma unroll
    for (int t = 0; t < 16; t++) {
        float acc = Xr[0] + ((t & 1) ? -Xr[8] : Xr[8]);
#pragma unroll
        for (int f = 1; f < 8; f++) {
            int kk = (f * t) & 15;
            acc = fmaf(2.0f * Xr[f], COS16[kk], acc);
            acc = fmaf(-2.0f * Xi[f], SIN16[kk], acc);
        }
        acc *= (1.0f / 16.0f);
        acc = fmaxf(acc, 0.0f);    // relu
        xt[t] = acc;
        ssum += acc;
    }

    float invs = 1.0f / ssum;      // ssum > 0: X[0] = exp(real) > 0 pre-relu
    float* op = out + (size_t)p * 16;
    // flip along time axis, normalized, vectorized stores
    float4* op4 = (float4*)op;
    op4[0] = make_float4(xt[15] * invs, xt[14] * invs, xt[13] * invs, xt[12] * invs);
    op4[1] = make_float4(xt[11] * invs, xt[10] * invs, xt[9]  * invs, xt[8]  * invs);
    op4[2] = make_float4(xt[7]  * invs, xt[6]  * invs, xt[5]  * invs, xt[4]  * invs);
    op4[3] = make_float4(xt[3]  * invs, xt[2]  * invs, xt[1]  * invs, xt[0]  * invs);
}

extern "C" void kernel_launch(void* const* d_in, const int* in_sizes, int n_in,
                              void* d_out, int out_size, void* d_ws, size_t ws_size,
                              hipStream_t stream) {
    const float* params = (const float*)d_in[0];
    const int* path_idxs = (const int*)d_in[1];
    const int* path_nodes = (const int*)d_in[2];
    float* out = (float*)d_out;
    float2* lg = (float2*)d_ws;   // needs N_NODES * NODE_STRIDE * 8 = 8 MB

    {
        int threads = 256;
        int blocks = (N_NODES + threads - 1) / threads;
        node_logfreq_kernel<<<blocks, threads, 0, stream>>>(params, lg);
    }
    {
        int threads = 256;
        int blocks = (N_PATHS + threads - 1) / threads;
        path_kernel<<<blocks, threads, 0, stream>>>(path_idxs, path_nodes, lg, out);
    }
}

// Round 2
// 178.192 us; speedup vs baseline: 1.6339x; 1.6339x over previous
//
#include <hip/hip_runtime.h>
#include <math.h>

#define N_NODES  100000
#define N_PATHS  1000000
#define E_TOT    8000000
#define NF       9          // rfft bins for n=16

// cos/sin(2*pi*k/16)
__device__ __constant__ float COS16[16] = {
  1.0f,  0.92387953f,  0.70710678f,  0.38268343f,  0.0f, -0.38268343f, -0.70710678f, -0.92387953f,
 -1.0f, -0.92387953f, -0.70710678f, -0.38268343f,  0.0f,  0.38268343f,  0.70710678f,  0.92387953f };
__device__ __constant__ float SIN16[16] = {
  0.0f,  0.38268343f,  0.70710678f,  0.92387953f,  1.0f,  0.92387953f,  0.70710678f,  0.38268343f,
  0.0f, -0.38268343f, -0.70710678f, -0.92387953f, -1.0f, -0.92387953f, -0.70710678f, -0.38268343f };

// Stage 1: r[n] = exp(-1/k), k = params[n]+0.5.
// Closed form: rfft16 of x[t]=r^t/k is A/(1 - r e^{-i w_f}), A=(1-r^16)/k.
// A>0 cancels under relu+normalize, so r alone captures the whole node.
__global__ void node_r_kernel(const float* __restrict__ params,
                              float* __restrict__ rtab) {
    int n = blockIdx.x * blockDim.x + threadIdx.x;
    if (n >= N_NODES) return;
    float k = params[n] + 0.5f;
    rtab[n] = expf(-1.0f / k);
}

// Stage 2: segment starts via boundary scatter (pidx is sorted).
// start[p] = first e with pidx[e] >= p; start[N_PATHS] = E_TOT.
__global__ void seg_starts_kernel(const int* __restrict__ pidx,
                                  int* __restrict__ start) {
    int e = blockIdx.x * blockDim.x + threadIdx.x;
    if (e >= E_TOT) return;
    int cur = pidx[e];
    int prev = (e == 0) ? -1 : pidx[e - 1];
    for (int p = prev + 1; p <= cur; ++p) start[p] = e;
    if (e == E_TOT - 1) {
        for (int p = cur + 1; p <= N_PATHS; ++p) start[p] = E_TOT;
    }
}

// Stage 3: one thread per path. Running complex products of the 9
// denominator terms, reciprocal, irfft(16), relu, flip, normalize.
__global__ void path_kernel(const int* __restrict__ start,
                            const int* __restrict__ pnode,
                            const float* __restrict__ rtab,
                            float* __restrict__ out) {
    int p = blockIdx.x * blockDim.x + threadIdx.x;
    if (p >= N_PATHS) return;

    int s0 = start[p];
    int s1 = start[p + 1];

    // term(f) = 1 - r*cos(w_f) + i*r*sin(w_f), w_f = 2*pi*f/16
    // f=0 -> (1-r) real; f=8 -> (1+r) real; f=1..7 complex.
    float c1 = COS16[1], c2 = COS16[2], c3 = COS16[3],
          c5 = COS16[5], c6 = COS16[6], c7 = COS16[7];
    float sn1 = SIN16[1], sn2 = SIN16[2], sn3 = SIN16[3], sn4 = SIN16[4],
          sn5 = SIN16[5], sn6 = SIN16[6], sn7 = SIN16[7];

    float d0 = 1.0f, d8 = 1.0f;
    float dr[7], di[7];
#pragma unroll
    for (int f = 0; f < 7; f++) { dr[f] = 1.0f; di[f] = 0.0f; }

    for (int e = s0; e < s1; e++) {
        int node = pnode[e];
        float r = rtab[node];
        d0 = fmaf(-d0, r, d0);          // *= (1 - r)
        d8 = fmaf( d8, r, d8);          // *= (1 + r)
        float tr, ti, nr;
        // f=1
        tr = fmaf(-r, c1, 1.0f); ti = r * sn1;
        nr = dr[0]*tr - di[0]*ti; di[0] = dr[0]*ti + di[0]*tr; dr[0] = nr;
        // f=2
        tr = fmaf(-r, c2, 1.0f); ti = r * sn2;
        nr = dr[1]*tr - di[1]*ti; di[1] = dr[1]*ti + di[1]*tr; dr[1] = nr;
        // f=3
        tr = fmaf(-r, c3, 1.0f); ti = r * sn3;
        nr = dr[2]*tr - di[2]*ti; di[2] = dr[2]*ti + di[2]*tr; dr[2] = nr;
        // f=4: cos=0 -> term = 1 + i*r
        ti = r * sn4;
        nr = dr[3] - di[3]*ti; di[3] = fmaf(dr[3], ti, di[3]); dr[3] = nr;
        // f=5
        tr = fmaf(-r, c5, 1.0f); ti = r * sn5;
        nr = dr[4]*tr - di[4]*ti; di[4] = dr[4]*ti + di[4]*tr; dr[4] = nr;
        // f=6
        tr = fmaf(-r, c6, 1.0f); ti = r * sn6;
        nr = dr[5]*tr - di[5]*ti; di[5] = dr[5]*ti + di[5]*tr; dr[5] = nr;
        // f=7
        tr = fmaf(-r, c7, 1.0f); ti = r * sn7;
        nr = dr[6]*tr - di[6]*ti; di[6] = dr[6]*ti + di[6]*tr; dr[6] = nr;
    }

    // H(f) = s * conj(D(f)) / |D(f)|^2, s = D(0) = d0 (positive real).
    // H(0) = 1 exactly; |H(f)| <= 1 (|D(f)| >= D(0) term-by-term).
    float Xr[NF], Xi[NF];
    Xr[0] = 1.0f; Xi[0] = 0.0f;
#pragma unroll
    for (int f = 1; f < 8; f++) {
        float a = dr[f - 1], b = di[f - 1];
        float m = fmaf(a, a, b * b);
        float inv = d0 / m;
        Xr[f] =  a * inv;
        Xi[f] = -b * inv;
    }
    Xr[8] = d0 / d8; Xi[8] = 0.0f;

    // irfft n=16: x[t] = (1/16)[X0 + (-1)^t X8 + 2*sum_{f=1..7}(Xr cos - Xi sin)(2pi f t/16)]
    float xt[16];
    float ssum = 0.0f;
#pragma unroll
    for (int t = 0; t < 16; t++) {
        float acc = Xr[0] + ((t & 1) ? -Xr[8] : Xr[8]);
#pragma unroll
        for (int f = 1; f < 8; f++) {
            int kk = (f * t) & 15;
            acc = fmaf(2.0f * Xr[f], COS16[kk], acc);
            acc = fmaf(-2.0f * Xi[f], SIN16[kk], acc);
        }
        acc *= (1.0f / 16.0f);
        acc = fmaxf(acc, 0.0f);    // relu
        xt[t] = acc;
        ssum += acc;
    }

    float invs = 1.0f / ssum;      // ssum > 0: X0 contribution is positive
    float4* op4 = (float4*)(out + (size_t)p * 16);
    op4[0] = make_float4(xt[15] * invs, xt[14] * invs, xt[13] * invs, xt[12] * invs);
    op4[1] = make_float4(xt[11] * invs, xt[10] * invs, xt[9]  * invs, xt[8]  * invs);
    op4[2] = make_float4(xt[7]  * invs, xt[6]  * invs, xt[5]  * invs, xt[4]  * invs);
    op4[3] = make_float4(xt[3]  * invs, xt[2]  * invs, xt[1]  * invs, xt[0]  * invs);
}

extern "C" void kernel_launch(void* const* d_in, const int* in_sizes, int n_in,
                              void* d_out, int out_size, void* d_ws, size_t ws_size,
                              hipStream_t stream) {
    const float* params = (const float*)d_in[0];
    const int* path_idxs = (const int*)d_in[1];
    const int* path_nodes = (const int*)d_in[2];
    float* out = (float*)d_out;

    // workspace layout: rtab [N_NODES floats] | start [N_PATHS+1 ints]
    float* rtab = (float*)d_ws;
    int* start = (int*)((char*)d_ws + ((N_NODES * sizeof(float) + 255) & ~255));

    {
        int threads = 256;
        int blocks = (N_NODES + threads - 1) / threads;
        node_r_kernel<<<blocks, threads, 0, stream>>>(params, rtab);
    }
    {
        int threads = 256;
        int blocks = (E_TOT + threads - 1) / threads;
        seg_starts_kernel<<<blocks, threads, 0, stream>>>(path_idxs, start);
    }
    {
        int threads = 256;
        int blocks = (N_PATHS + threads - 1) / threads;
        path_kernel<<<blocks, threads, 0, stream>>>(start, path_nodes, rtab, out);
    }
}

// Round 3
// 162.213 us; speedup vs baseline: 1.7948x; 1.0985x over previous
//
#include <hip/hip_runtime.h>
#include <math.h>

#define N_NODES  100000
#define N_PATHS  1000000
#define E_TOT    8000000
#define NF       9          // rfft bins for n=16
#define CHUNK    4096       // LDS staging chunk (floats); block entry range ~2048±45

// cos/sin(2*pi*k/16)
__device__ __constant__ float COS16[16] = {
  1.0f,  0.92387953f,  0.70710678f,  0.38268343f,  0.0f, -0.38268343f, -0.70710678f, -0.92387953f,
 -1.0f, -0.92387953f, -0.70710678f, -0.38268343f,  0.0f,  0.38268343f,  0.70710678f,  0.92387953f };
__device__ __constant__ float SIN16[16] = {
  0.0f,  0.38268343f,  0.70710678f,  0.92387953f,  1.0f,  0.92387953f,  0.70710678f,  0.38268343f,
  0.0f, -0.38268343f, -0.70710678f, -0.92387953f, -1.0f, -0.92387953f, -0.70710678f, -0.38268343f };

// Stage 1: r[n] = exp(-1/k), k = params[n]+0.5.
// rfft16 of x[t]=r^t/k is A/(1 - r e^{-i w_f}); positive real A cancels
// under relu+normalize, so r alone captures the node.
__global__ void node_r_kernel(const float* __restrict__ params,
                              float* __restrict__ rtab) {
    int n = blockIdx.x * blockDim.x + threadIdx.x;
    if (n >= N_NODES) return;
    float k = params[n] + 0.5f;
    rtab[n] = expf(-1.0f / k);
}

// Stage 2: segment starts via boundary scatter, int4-vectorized.
// start[p] = first e with pidx[e] >= p; start[N_PATHS] = E_TOT.
__device__ __forceinline__ void put_bounds(int a, int b, int e, int* __restrict__ start) {
    for (int p = a + 1; p <= b; ++p) start[p] = e;
}
__global__ void seg_starts_kernel(const int* __restrict__ pidx,
                                  int* __restrict__ start) {
    int q = blockIdx.x * blockDim.x + threadIdx.x;
    if (q >= E_TOT / 4) return;
    int e = q * 4;
    int4 v = ((const int4*)pidx)[q];
    int prev = (e == 0) ? -1 : pidx[e - 1];
    put_bounds(prev, v.x, e,     start);
    put_bounds(v.x,  v.y, e + 1, start);
    put_bounds(v.y,  v.z, e + 2, start);
    put_bounds(v.z,  v.w, e + 3, start);
    if (e + 4 == E_TOT) {
        for (int p = v.w + 1; p <= N_PATHS; ++p) start[p] = E_TOT;
    }
}

// Stage 3: block-cooperative. Each block owns 256 consecutive paths whose
// entries form one contiguous range (pidx sorted). Stage r for the range
// into LDS with coalesced pnode reads; each thread walks its segment from
// LDS, maintaining 9 complex running products; then irfft/relu/flip/norm.
__global__ __launch_bounds__(256) void path_kernel(const int* __restrict__ start,
                                                   const int* __restrict__ pnode,
                                                   const float* __restrict__ rtab,
                                                   float* __restrict__ out) {
    __shared__ float lds_r[CHUNK];

    int p0 = blockIdx.x * 256;
    int p  = p0 + threadIdx.x;
    int pend = (p0 + 256 < N_PATHS) ? p0 + 256 : N_PATHS;

    int blk_s = start[p0];
    int blk_e = start[pend];
    int s0 = 0, s1 = 0;
    if (p < N_PATHS) { s0 = start[p]; s1 = start[p + 1]; }

    float c1 = COS16[1], c2 = COS16[2], c3 = COS16[3],
          c5 = COS16[5], c6 = COS16[6], c7 = COS16[7];
    float sn1 = SIN16[1], sn2 = SIN16[2], sn3 = SIN16[3], sn4 = SIN16[4],
          sn5 = SIN16[5], sn6 = SIN16[6], sn7 = SIN16[7];

    float d0 = 1.0f, d8 = 1.0f;
    float dr[7], di[7];
#pragma unroll
    for (int f = 0; f < 7; f++) { dr[f] = 1.0f; di[f] = 0.0f; }

    for (int base = blk_s; base < blk_e; base += CHUNK) {
        int len = (blk_e - base < CHUNK) ? (blk_e - base) : CHUNK;
        __syncthreads();
        for (int i = threadIdx.x; i < len; i += 256) {
            lds_r[i] = rtab[pnode[base + i]];   // coalesced pnode, L2 rtab gather
        }
        __syncthreads();

        int lo = (s0 > base) ? s0 : base;
        int hi = (s1 < base + len) ? s1 : base + len;
        for (int e = lo; e < hi; e++) {
            float r = lds_r[e - base];
            d0 = fmaf(-d0, r, d0);          // *= (1 - r)
            d8 = fmaf( d8, r, d8);          // *= (1 + r)
            float tr, ti, nr;
            tr = fmaf(-r, c1, 1.0f); ti = r * sn1;
            nr = dr[0]*tr - di[0]*ti; di[0] = dr[0]*ti + di[0]*tr; dr[0] = nr;
            tr = fmaf(-r, c2, 1.0f); ti = r * sn2;
            nr = dr[1]*tr - di[1]*ti; di[1] = dr[1]*ti + di[1]*tr; dr[1] = nr;
            tr = fmaf(-r, c3, 1.0f); ti = r * sn3;
            nr = dr[2]*tr - di[2]*ti; di[2] = dr[2]*ti + di[2]*tr; dr[2] = nr;
            ti = r * sn4;                   // f=4: term = 1 + i*r
            nr = dr[3] - di[3]*ti; di[3] = fmaf(dr[3], ti, di[3]); dr[3] = nr;
            tr = fmaf(-r, c5, 1.0f); ti = r * sn5;
            nr = dr[4]*tr - di[4]*ti; di[4] = dr[4]*ti + di[4]*tr; dr[4] = nr;
            tr = fmaf(-r, c6, 1.0f); ti = r * sn6;
            nr = dr[5]*tr - di[5]*ti; di[5] = dr[5]*ti + di[5]*tr; dr[5] = nr;
            tr = fmaf(-r, c7, 1.0f); ti = r * sn7;
            nr = dr[6]*tr - di[6]*ti; di[6] = dr[6]*ti + di[6]*tr; dr[6] = nr;
        }
    }

    if (p >= N_PATHS) return;

    // H(f) = d0 * conj(D(f)) / |D(f)|^2; H(0)=1, |H(f)| <= 1.
    float Xr[NF], Xi[NF];
    Xr[0] = 1.0f; Xi[0] = 0.0f;
#pragma unroll
    for (int f = 1; f < 8; f++) {
        float a = dr[f - 1], b = di[f - 1];
        float m = fmaf(a, a, b * b);
        float inv = d0 / m;
        Xr[f] =  a * inv;
        Xi[f] = -b * inv;
    }
    Xr[8] = d0 / d8; Xi[8] = 0.0f;

    // irfft n=16, relu, running sum
    float xt[16];
    float ssum = 0.0f;
#pragma unroll
    for (int t = 0; t < 16; t++) {
        float acc = Xr[0] + ((t & 1) ? -Xr[8] : Xr[8]);
#pragma unroll
        for (int f = 1; f < 8; f++) {
            int kk = (f * t) & 15;
            acc = fmaf(2.0f * Xr[f], COS16[kk], acc);
            acc = fmaf(-2.0f * Xi[f], SIN16[kk], acc);
        }
        acc *= (1.0f / 16.0f);
        acc = fmaxf(acc, 0.0f);
        xt[t] = acc;
        ssum += acc;
    }

    float invs = 1.0f / ssum;
    float4* op4 = (float4*)(out + (size_t)p * 16);
    op4[0] = make_float4(xt[15] * invs, xt[14] * invs, xt[13] * invs, xt[12] * invs);
    op4[1] = make_float4(xt[11] * invs, xt[10] * invs, xt[9]  * invs, xt[8]  * invs);
    op4[2] = make_float4(xt[7]  * invs, xt[6]  * invs, xt[5]  * invs, xt[4]  * invs);
    op4[3] = make_float4(xt[3]  * invs, xt[2]  * invs, xt[1]  * invs, xt[0]  * invs);
}

extern "C" void kernel_launch(void* const* d_in, const int* in_sizes, int n_in,
                              void* d_out, int out_size, void* d_ws, size_t ws_size,
                              hipStream_t stream) {
    const float* params = (const float*)d_in[0];
    const int* path_idxs = (const int*)d_in[1];
    const int* path_nodes = (const int*)d_in[2];
    float* out = (float*)d_out;

    // workspace: rtab [N_NODES floats] | start [N_PATHS+1 ints]
    float* rtab = (float*)d_ws;
    int* start = (int*)((char*)d_ws + ((N_NODES * sizeof(float) + 255) & ~255));

    {
        int threads = 256;
        int blocks = (N_NODES + threads - 1) / threads;
        node_r_kernel<<<blocks, threads, 0, stream>>>(params, rtab);
    }
    {
        int threads = 256;
        int blocks = (E_TOT / 4 + threads - 1) / threads;
        seg_starts_kernel<<<blocks, threads, 0, stream>>>(path_idxs, start);
    }
    {
        int threads = 256;
        int blocks = (N_PATHS + 255) / 256;
        path_kernel<<<blocks, threads, 0, stream>>>(start, path_nodes, rtab, out);
    }
}